// Round 4
// baseline (233.574 us; speedup 1.0000x reference)
//
#include <hip/hip_runtime.h>
#include <hip/hip_bf16.h>

constexpr int kB = 8, kN = 8192, kS = 2048;
constexpr int kD1 = 128, kD2 = 256, kCin = 384, kM0 = 256, kM1 = 128;
constexpr float kEps = 1e-5f;

typedef float f32x4 __attribute__((ext_vector_type(4)));
typedef short bf16x8 __attribute__((ext_vector_type(8)));
typedef unsigned short u16x4 __attribute__((ext_vector_type(4)));

__device__ inline unsigned short f2bf(float f) {
    __hip_bfloat16 h = __float2bfloat16(f);
    return *reinterpret_cast<unsigned short*>(&h);
}
__device__ inline float bf2f(unsigned short u) {
    unsigned int v = (unsigned int)u << 16;
    return *reinterpret_cast<float*>(&v);
}

// ---------------- Transpose points2 [b][c][s] -> p2t [b][s][c] (f32) -------
__global__ __launch_bounds__(256) void transpose_p2_kernel(
    const float* __restrict__ in, float* __restrict__ out)
{
    __shared__ float tl[64][69];
    const int s0 = blockIdx.x * 64, c0 = blockIdx.y * 64, b = blockIdx.z;
    const int t = threadIdx.x;
    const int rlo = t >> 4, rhi = t & 15;
#pragma unroll
    for (int r = 0; r < 4; ++r) {
        const int cl = rlo + r * 16;
        f32x4 v = *(const f32x4*)(in + ((size_t)(b * kD2 + c0 + cl)) * kS + s0 + rhi * 4);
#pragma unroll
        for (int j = 0; j < 4; ++j) tl[cl][rhi * 4 + j] = v[j];
    }
    __syncthreads();
#pragma unroll
    for (int r = 0; r < 4; ++r) {
        const int sl = rlo + r * 16;
        f32x4 v;
#pragma unroll
        for (int j = 0; j < 4; ++j) v[j] = tl[rhi * 4 + j][sl];
        *(f32x4*)(out + ((size_t)(b * kS + s0 + sl)) * kD2 + c0 + rhi * 4) = v;
    }
}

// ------------- Transpose points1 [b][c][n] -> xt[b][n][256+c] (bf16) -------
__global__ __launch_bounds__(256) void transpose_p1_kernel(
    const float* __restrict__ in, unsigned short* __restrict__ xt)
{
    __shared__ float tl[64][69];
    const int n0 = blockIdx.x * 64, c0 = blockIdx.y * 64, b = blockIdx.z;
    const int t = threadIdx.x;
    const int rlo = t >> 4, rhi = t & 15;
#pragma unroll
    for (int r = 0; r < 4; ++r) {
        const int cl = rlo + r * 16;
        f32x4 v = *(const f32x4*)(in + ((size_t)(b * kD1 + c0 + cl)) * kN + n0 + rhi * 4);
#pragma unroll
        for (int j = 0; j < 4; ++j) tl[cl][rhi * 4 + j] = v[j];
    }
    __syncthreads();
#pragma unroll
    for (int r = 0; r < 4; ++r) {
        const int nl = rlo + r * 16;
        u16x4 u;
#pragma unroll
        for (int j = 0; j < 4; ++j) u[j] = f2bf(tl[rhi * 4 + j][nl]);
        *(u16x4*)(xt + ((size_t)(b * kN + n0 + nl)) * kCin + 256 + c0 + rhi * 4) = u;
    }
}

// ---------------- 3-NN + interp: 2 lanes per query, broadcast LDS ----------
// One query per lane-pair: lane parity p scans sources s = 2i+p, so a wave's
// 64 lanes hit only 2 distinct LDS addresses per read -> broadcast (free),
// cutting LDS traffic ~30x vs per-lane-distinct reads (round-3 bottleneck).
// pass1: fp32 reduced dist d' = |s|^2 - 2p.s (order-preserving), branchless
//        med3/min top-3 chain per lane; pair-merge sorted triples -> m2;
//        cutoff = m2 + 1e-3 (fp32 err ~5e-5: provably admits true f64 top-3).
// pass2: rescan; candidates (df<=cutoff) take exact fp64 insert with index;
//        symmetric pair-merge with (d, idx) lexicographic order (stable ties).
__global__ __launch_bounds__(256) void knn_interp_kernel(
    const float* __restrict__ xyz1, const float* __restrict__ xyz2,
    const float* __restrict__ p2t, unsigned short* __restrict__ xt)
{
    __shared__ f32x4 sp[kS];                 // (sx,sy,sz,|s|^2) 32 KB
    const int b = blockIdx.x >> 6;           // 64 blocks per batch
    const int n0 = (blockIdx.x & 63) << 7;   // 128 queries per block
    const int t = threadIdx.x;
    const float* x2 = xyz2 + b * 3 * kS;
    for (int s = t; s < kS; s += 256) {
        float sx = x2[s], sy = x2[kS + s], sz = x2[2 * kS + s];
        f32x4 q = {sx, sy, sz, fmaf(sx, sx, fmaf(sy, sy, sz * sz))};
        sp[s] = q;
    }
    __syncthreads();
    const int q = t >> 1, par = t & 1;
    const int n = n0 + q;
    const float* x1 = xyz1 + b * 3 * kN;
    const float px = x1[n], py = x1[kN + n], pz = x1[2 * kN + n];
    const float ax = -2.f * px, ay = -2.f * py, az = -2.f * pz;

    // ---- pass 1: per-lane top-3 of d' over parity sources (single chain)
    float a0 = 1e30f, a1 = 1e30f, a2 = 1e30f;
    for (int i = 0; i < 1024; i += 8) {
#pragma unroll
        for (int j = 0; j < 8; ++j) {
            f32x4 qv = sp[2 * (i + j) + par];
            float e = fmaf(ax, qv[0], fmaf(ay, qv[1], fmaf(az, qv[2], qv[3])));
            float t1 = __builtin_amdgcn_fmed3f(e, a0, a1);
            float t2 = __builtin_amdgcn_fmed3f(e, a1, a2);
            a0 = fminf(a0, e); a1 = t1; a2 = t2;
        }
    }
    // merge sorted triples across the lane pair
    {
        float y0 = __shfl_xor(a0, 1), y1 = __shfl_xor(a1, 1), y2 = __shfl_xor(a2, 1);
        float z0 = fminf(a0, y0);
        float z1 = fminf(fmaxf(a0, y0), fminf(a1, y1));
        float z2 = fminf(fminf(fmaxf(a1, y0), fmaxf(a0, y1)), fminf(a2, y2));
        a0 = z0; a1 = z1; a2 = z2;
    }
    const float cutoff = a2 + 1e-3f;

    // ---- pass 2: exact fp64 top-3 with indices among filtered candidates
    double d0 = 1e300, d1 = 1e300, d2 = 1e300;
    int i0 = 0, i1 = 0, i2 = 0;
    const double dpx = (double)px, dpy = (double)py, dpz = (double)pz;
    for (int i = 0; i < 1024; i += 2) {
#pragma unroll
        for (int j = 0; j < 2; ++j) {
            const int s = 2 * (i + j) + par;
            f32x4 qv = sp[s];
            float df = fmaf(ax, qv[0], fmaf(ay, qv[1], fmaf(az, qv[2], qv[3])));
            if (df <= cutoff) {
                double ex = dpx - (double)qv[0], ey = dpy - (double)qv[1], ez = dpz - (double)qv[2];
                double d = ex * ex + ey * ey + ez * ez;
                if (d < d2) {
                    if (d < d1) {
                        if (d < d0) { d2 = d1; i2 = i1; d1 = d0; i1 = i0; d0 = d; i0 = s; }
                        else        { d2 = d1; i2 = i1; d1 = d;  i1 = s; }
                    } else          { d2 = d;  i2 = s; }
                }
            }
        }
    }
    // symmetric pair merge with lexicographic (d, idx) order
    {
        double pd0 = __shfl_xor(d0, 1), pd1 = __shfl_xor(d1, 1), pd2 = __shfl_xor(d2, 1);
        int pi0 = __shfl_xor(i0, 1), pi1 = __shfl_xor(i1, 1), pi2 = __shfl_xor(i2, 1);
#pragma unroll
        for (int m = 0; m < 3; ++m) {
            double pd = (m == 0) ? pd0 : (m == 1) ? pd1 : pd2;
            int pi = (m == 0) ? pi0 : (m == 1) ? pi1 : pi2;
            if (pd < d2 || (pd == d2 && pi < i2)) {
                if (pd < d1 || (pd == d1 && pi < i1)) {
                    if (pd < d0 || (pd == d0 && pi < i0)) {
                        d2 = d1; i2 = i1; d1 = d0; i1 = i0; d0 = pd; i0 = pi;
                    } else { d2 = d1; i2 = i1; d1 = pd; i1 = pi; }
                } else { d2 = pd; i2 = pi; }
            }
        }
    }
    const double r0 = 1.0 / (d0 + 1e-8), r1 = 1.0 / (d1 + 1e-8), r2 = 1.0 / (d2 + 1e-8);
    const double rs = 1.0 / (r0 + r1 + r2);
    const float w0 = (float)(r0 * rs), w1 = (float)(r1 * rs), w2 = (float)(r2 * rs);

    // gather: 3 contiguous 1 KB rows of p2t, pair-cooperative (32 chunks/lane)
    const f32x4* row0 = (const f32x4*)(p2t + ((size_t)(b * kS) + i0) * kD2);
    const f32x4* row1 = (const f32x4*)(p2t + ((size_t)(b * kS) + i1) * kD2);
    const f32x4* row2 = (const f32x4*)(p2t + ((size_t)(b * kS) + i2) * kD2);
    unsigned short* dst = xt + ((size_t)(b * kN) + n) * kCin;
#pragma unroll 4
    for (int j = 0; j < 32; ++j) {
        const int ch = par + 2 * j;                 // f32x4 chunk index (0..63)
        f32x4 v = w0 * row0[ch] + w1 * row1[ch] + w2 * row2[ch];
        u16x4 u = {f2bf(v[0]), f2bf(v[1]), f2bf(v[2]), f2bf(v[3])};
        *(u16x4*)(dst + ch * 4) = u;
    }
}

// ---------------- bf16 MFMA GEMM + BN-stats --------------------------------
// X rows [n][K] bf16. W [MTOT][K] f32 -> bf16 on stage. 128x128 tile, 4 waves,
// 16x16x32 MFMA, XOR-swizzled LDS.
// BNRELU: apply input-side scale/shift + relu while staging X.
// OUTMODE: 0 = bf16 Yb[b][n][m]; 2 = no store (stats-only pass);
//          3 = f32 Yf[b][m][n] with output-side scaleO/shiftO + relu.
// STATS: accumulate per-channel sum/sumsq (shuffle + LDS + global atomics).
__device__ inline int swz(int row, int ks) {   // ushort index of a 16B slot
    return row * 32 + ((ks ^ ((row >> 1) & 3)) << 3);
}

template <int K, int MTOT, bool BNRELU, int OUTMODE, bool STATS>
__global__ __launch_bounds__(256) void gemm_bn_kernel(
    const float* __restrict__ W, const unsigned short* __restrict__ X,
    const float* __restrict__ scale, const float* __restrict__ shift,
    const float* __restrict__ scaleO, const float* __restrict__ shiftO,
    unsigned short* __restrict__ Yb, float* __restrict__ Yf,
    float* __restrict__ gsum, float* __restrict__ gsq)
{
    constexpr int BM = 128, BN = 128;
    __shared__ unsigned short Al[BM * 32], Bl[BN * 32];   // 8 KB each, swizzled
    __shared__ float ssum[BM], ssq[BM];
    __shared__ float s_sc[K > 0 ? K : 1], s_sh[K > 0 ? K : 1];
    __shared__ float s_scO[BM], s_shO[BM];
    const int t = threadIdx.x;
    const int bn = blockIdx.x * BN, bo = blockIdx.y * BM, b = blockIdx.z;
    const int l = t & 63, w = t >> 6;
    const int wm = (w >> 1) * 64, wn = (w & 1) * 64;
    const int lrow = l & 15, lks = l >> 4;

    if constexpr (BNRELU) {
        if (t < K) { s_sc[t] = scale[t]; s_sh[t] = shift[t]; }
    }
    if constexpr (OUTMODE == 3) {
        if (t < BM) { s_scO[t] = scaleO[bo + t]; s_shO[t] = shiftO[bo + t]; }
    }
    if constexpr (STATS) {
        if (t < BM) { ssum[t] = 0.f; ssq[t] = 0.f; }
    }
    __syncthreads();

    f32x4 acc[4][4] = {};
    for (int k0 = 0; k0 < K; k0 += 32) {
#pragma unroll
        for (int r = 0; r < 2; ++r) {
            const int sid = t + r * 256;
            const int m = sid >> 2, ks = sid & 3;
            const float* wp = W + (size_t)(bo + m) * K + k0 + ks * 8;
            f32x4 wa = *(const f32x4*)wp, wb = *(const f32x4*)(wp + 4);
            bf16x8 u;
#pragma unroll
            for (int j = 0; j < 4; ++j) { u[j] = (short)f2bf(wa[j]); u[j + 4] = (short)f2bf(wb[j]); }
            *(bf16x8*)(Al + swz(m, ks)) = u;
        }
#pragma unroll
        for (int r = 0; r < 2; ++r) {
            const int sid = t + r * 256;
            const int nl = sid >> 2, ks = sid & 3;
            bf16x8 v = *(const bf16x8*)(X + ((size_t)(b * kN) + bn + nl) * K + k0 + ks * 8);
            if constexpr (BNRELU) {
#pragma unroll
                for (int j = 0; j < 8; ++j) {
                    const int ch = k0 + ks * 8 + j;
                    float f = fmaxf(fmaf(bf2f((unsigned short)v[j]), s_sc[ch], s_sh[ch]), 0.f);
                    v[j] = (short)f2bf(f);
                }
            }
            *(bf16x8*)(Bl + swz(nl, ks)) = v;
        }
        __syncthreads();
        bf16x8 af[4], bfr[4];
#pragma unroll
        for (int f = 0; f < 4; ++f) af[f]  = *(const bf16x8*)(Al + swz(wm + f * 16 + lrow, lks));
#pragma unroll
        for (int f = 0; f < 4; ++f) bfr[f] = *(const bf16x8*)(Bl + swz(wn + f * 16 + lrow, lks));
#pragma unroll
        for (int mi = 0; mi < 4; ++mi)
#pragma unroll
            for (int ni = 0; ni < 4; ++ni)
                acc[mi][ni] = __builtin_amdgcn_mfma_f32_16x16x32_bf16(af[mi], bfr[ni], acc[mi][ni], 0, 0, 0);
        __syncthreads();
    }

    if constexpr (STATS) {
#pragma unroll
        for (int mi = 0; mi < 4; ++mi) {
#pragma unroll
            for (int r = 0; r < 4; ++r) {
                float ps = 0.f, pq = 0.f;
#pragma unroll
                for (int ni = 0; ni < 4; ++ni) { float v = acc[mi][ni][r]; ps += v; pq += v * v; }
#pragma unroll
                for (int off = 1; off < 16; off <<= 1) { ps += __shfl_xor(ps, off); pq += __shfl_xor(pq, off); }
                if (lrow == 0) {
                    const int m = wm + mi * 16 + lks * 4 + r;
                    atomicAdd(&ssum[m], ps); atomicAdd(&ssq[m], pq);
                }
            }
        }
    }

    if constexpr (OUTMODE == 0) {
#pragma unroll
        for (int mi = 0; mi < 4; ++mi)
#pragma unroll
            for (int ni = 0; ni < 4; ++ni) {
                const int m = bo + wm + mi * 16 + lks * 4;
                const int n = bn + wn + ni * 16 + lrow;
                u16x4 u = {f2bf(acc[mi][ni][0]), f2bf(acc[mi][ni][1]),
                           f2bf(acc[mi][ni][2]), f2bf(acc[mi][ni][3])};
                *(u16x4*)(Yb + ((size_t)(b * kN) + n) * MTOT + m) = u;
            }
    } else if constexpr (OUTMODE == 3) {
#pragma unroll
        for (int mi = 0; mi < 4; ++mi)
#pragma unroll
            for (int ni = 0; ni < 4; ++ni) {
                const int n = bn + wn + ni * 16 + lrow;
#pragma unroll
                for (int r = 0; r < 4; ++r) {
                    const int ml = wm + mi * 16 + lks * 4 + r;
                    float v = fmaxf(fmaf(acc[mi][ni][r], s_scO[ml], s_shO[ml]), 0.f);
                    Yf[((size_t)(b * MTOT) + bo + ml) * kN + n] = v;
                }
            }
    }
    if constexpr (STATS) {
        __syncthreads();
        if (t < BM) {
            atomicAdd(&gsum[bo + t], ssum[t]);
            atomicAdd(&gsq[bo + t], ssq[t]);
        }
    }
}

// ---------------- BN stat finalize -----------------------------------------
__global__ void bn_finalize_kernel(const float* __restrict__ gsum, const float* __restrict__ gsq,
                                   const float* __restrict__ g, const float* __restrict__ be,
                                   float* __restrict__ scale, float* __restrict__ shift, int M)
{
    int t = threadIdx.x;
    if (t < M) {
        const float invn = 1.0f / 65536.0f;
        float mean = gsum[t] * invn;
        float var = gsq[t] * invn - mean * mean;   // biased var
        float sc = g[t] * rsqrtf(var + kEps);
        scale[t] = sc;
        shift[t] = fmaf(-mean, sc, be[t]);
    }
}

extern "C" void kernel_launch(void* const* d_in, const int* in_sizes, int n_in,
                              void* d_out, int out_size, void* d_ws, size_t ws_size,
                              hipStream_t stream)
{
    const float* xyz1    = (const float*)d_in[0];
    const float* xyz2    = (const float*)d_in[1];
    const float* points1 = (const float*)d_in[2];
    const float* points2 = (const float*)d_in[3];
    const float* w0      = (const float*)d_in[4];
    // d_in[5] = b0, d_in[9] = b1: conv biases cancel in BatchNorm -> unused
    const float* g0      = (const float*)d_in[6];
    const float* be0     = (const float*)d_in[7];
    const float* w1      = (const float*)d_in[8];
    const float* g1      = (const float*)d_in[10];
    const float* be1     = (const float*)d_in[11];
    float* out = (float*)d_out;

    char* ws = (char*)d_ws;
    unsigned short* xt  = (unsigned short*)ws;                           // 48 MiB  [B][N][384] bf16
    float* p2t          = (float*)(ws + (size_t)50331648);               // 16 MiB  [B][S][256] f32
    unsigned short* y0t = (unsigned short*)(ws + (size_t)67108864);      // 32 MiB  [B][N][256] bf16
    float* stats        = (float*)(ws + (size_t)100663296);
    float* sum0 = stats,          *sq0 = stats + 256;
    float* sum1 = stats + 512,    *sq1 = stats + 640;
    float* scale0 = stats + 768,  *shift0 = stats + 1024;
    float* scale1 = stats + 1280, *shift1 = stats + 1408;

    hipMemsetAsync(stats, 0, 768 * sizeof(float), stream);
    transpose_p2_kernel<<<dim3(32, 4, 8), 256, 0, stream>>>(points2, p2t);
    transpose_p1_kernel<<<dim3(128, 2, 8), 256, 0, stream>>>(points1, xt);
    knn_interp_kernel<<<512, 256, 0, stream>>>(xyz1, xyz2, p2t, xt);
    gemm_bn_kernel<kCin, kM0, false, 0, true><<<dim3(64, 2, 8), 256, 0, stream>>>(
        w0, xt, nullptr, nullptr, nullptr, nullptr, y0t, nullptr, sum0, sq0);
    bn_finalize_kernel<<<1, 256, 0, stream>>>(sum0, sq0, g0, be0, scale0, shift0, 256);
    gemm_bn_kernel<kM0, kM1, true, 2, true><<<dim3(64, 1, 8), 256, 0, stream>>>(
        w1, y0t, scale0, shift0, nullptr, nullptr, nullptr, nullptr, sum1, sq1);
    bn_finalize_kernel<<<1, 128, 0, stream>>>(sum1, sq1, g1, be1, scale1, shift1, 128);
    gemm_bn_kernel<kM0, kM1, true, 3, false><<<dim3(64, 1, 8), 256, 0, stream>>>(
        w1, y0t, scale0, shift0, scale1, shift1, nullptr, out, nullptr, nullptr);
}